// Round 9
// baseline (258.883 us; speedup 1.0000x reference)
//
#include <hip/hip_runtime.h>

#define D 64
#define K 1024
#define NPTS 65536
#define OUT_ELEMS (NPTS * D)

typedef _Float16 f16x8 __attribute__((ext_vector_type(8)));
typedef float    f32x4 __attribute__((ext_vector_type(4)));

#define SCL  4096.0f            // 2^12
#define ISCL 0.000244140625f    // 2^-12

// d_ws layout (bytes): eT f32[K][64] @0 (262144) | enorm_half f32[K] @262144
// (4096) | ehf f16 frag-major @266240 (131072) | elf @397312 | end 528384.
//
// Fragment-major layout: for code k, dim d:
//   ct=k>>4, col=k&15, HH=d>>5, r=(d>>3)&3, j=d&7, lane=r*16+col
//   off = ((ct*2+HH)*64 + lane)*8 + j
// Main-loop lane (quad,m) reads its 16B f16x8 B-fragment for tile ct,
// K-half HH at ehf + (ct*2+HH)*512 + lane*8.

// Scaled f16 2-way split: v = h + ls*2^-12. h = RN16(v); ls = RN16((v-h)*2^12)
// is normal-range -> no subnormal-flush hazard; residual ~2^-24|v|.
static __device__ __forceinline__ void split16(float v, _Float16& h, _Float16& ls) {
    h = (_Float16)v;
    const float r = (v - (float)h) * SCL;   // exact scaling (pow2)
    ls = (_Float16)r;
}

// ---------------------------------------------------------------------------
// Prep: tiled transpose emb[D][K] -> eT[K][D] f32 (exact rows for the output
// gather) + fragment-major f16 h/ls arrays + enorm_half[k] = 0.5*||e_k||^2 in
// numpy axis-0 order; zero the loss slot.
// ---------------------------------------------------------------------------
__global__ __launch_bounds__(256) void vq_prep(const float* __restrict__ emb,
                                               float* __restrict__ eT,
                                               float* __restrict__ enorm_h,
                                               _Float16* __restrict__ ehf,
                                               _Float16* __restrict__ elf,
                                               float* __restrict__ loss_out) {
    __shared__ float tile[64][65];
    const int t    = threadIdx.x;
    const int lane = t & 63;
    const int quad = t >> 6;
    const int k0   = blockIdx.x * 64;

#pragma unroll
    for (int i = 0; i < 16; ++i) {
        const int d = i * 4 + quad;
        tile[d][lane] = emb[d * K + k0 + lane];
    }
    __syncthreads();

    const int kk = t >> 2, c = t & 3;
    const int krow = k0 + kk;
    const int ct   = krow >> 4, col = krow & 15;
#pragma unroll
    for (int j = 0; j < 16; ++j) {
        const int d = c * 16 + j;
        const float v = tile[d][kk];
        eT[krow * D + d] = v;
        _Float16 h, ls;
        split16(v, h, ls);
        const int off = ((ct * 2 + (d >> 5)) * 64 + ((d >> 3) & 3) * 16 + col) * 8
                        + (d & 7);
        ehf[off] = h; elf[off] = ls;
    }

    if (t < 64) {   // np add.reduce axis 0: sequential over d
        float s = __fmul_rn(tile[0][t], tile[0][t]);
        for (int dd = 1; dd < D; ++dd)
            s = __fadd_rn(s, __fmul_rn(tile[dd][t], tile[dd][t]));
        enorm_h[k0 + t] = 0.5f * s;
    }
    if (blockIdx.x == 0 && t == 0) *loss_out = 0.0f;
}

static __device__ __forceinline__ float sq8(float a, float b, float c, float d,
                                            float e, float f, float g, float h) {
    float r = __fmul_rn(a, a);
    r = __fadd_rn(r, __fmul_rn(b, b));
    r = __fadd_rn(r, __fmul_rn(c, c));
    r = __fadd_rn(r, __fmul_rn(d, d));
    r = __fadd_rn(r, __fmul_rn(e, e));
    r = __fadd_rn(r, __fmul_rn(f, f));
    r = __fadd_rn(r, __fmul_rn(g, g));
    r = __fadd_rn(r, __fmul_rn(h, h));
    return r;
}

#define PINF(v)  asm volatile("" : "+v"(v))
#define PINFA(v) asm volatile("" : "+a"(v))   // pin to AGPR (unified file)

#define MF(A, B, C) __builtin_amdgcn_mfma_f32_16x16x32_f16(A, B, C, 0, 0, 0)

#define MKFRAG16(FH, FS, U0, U1) {                        \
    _Float16 h_, s_;                                      \
    split16(U0.x, h_, s_); FH[0]=h_; FS[0]=s_;            \
    split16(U0.y, h_, s_); FH[1]=h_; FS[1]=s_;            \
    split16(U0.z, h_, s_); FH[2]=h_; FS[2]=s_;            \
    split16(U0.w, h_, s_); FH[3]=h_; FS[3]=s_;            \
    split16(U1.x, h_, s_); FH[4]=h_; FS[4]=s_;            \
    split16(U1.y, h_, s_); FH[5]=h_; FS[5]=s_;            \
    split16(U1.z, h_, s_); FH[6]=h_; FS[6]=s_;            \
    split16(U1.w, h_, s_); FH[7]=h_; FS[7]=s_; }

// ---------------------------------------------------------------------------
// Main (R19): R15 base + AGPR-pinned A-frags + 2-iteration-deep B prefetch.
// R17/R18 post-mortem: both "staggers" spilled because loads can only target
// the ARCH-VGPR half of the 128-reg unified budget (compiler splits 64/64;
// rocprof shows VGPR_Count=64 in every clean build). The loaded working set,
// not the total ledger, is the binding budget. R15's residual wall: ~1500
// cyc/iter exposed memory wait (1-body prefetch slack ~400cyc < congested L2
// latency with 16 waves/CU). Fix:
//   (1) A-frags + ZERO pinned to AGPR ("+a") — legal MFMA operands on the
//       gfx950 unified file, read-only after phase A; frees 36 VGPRs.
//   (2) 3-buffer B prefetch, 2 tiles deep (30 tiles = 10x3 rolled loop + 2
//       peeled): load->use slack ~2 bodies (~850cyc). enorm load moved
//       on-demand to tile top (issued ~200cyc before its single use).
//   (3) setprio(1/0) around the 12-MFMA cluster (free-running waves).
// VGPR half: B 48 + bk/bc 16 + addr ~14 = ~78; AGPR half: A 32 + ZERO 4 +
// acc 16 = 52; unified ~126 <= 128.
// Numerics bit-identical to R15: same tile order 0..31, same MFMA chains,
// same AC1 form kv = fma(-ISCL, c, enh - m), same argmin/loss/epilogue.
// ---------------------------------------------------------------------------
__global__ __launch_bounds__(512, 4) void vq_main(const float* __restrict__ x,
        const float* __restrict__ eT, const float* __restrict__ enorm_h,
        const _Float16* __restrict__ ehf, const _Float16* __restrict__ elf,
        float* __restrict__ out, float* __restrict__ loss_out) {
    // LDS: rpart 128x8 f32 @0 (4096) | swin 128 i32 @4096 (512) |
    //      skey 128x33 f32 @4608 (16896) | sct 128x33 i32 @21504 (16896) |
    //      end 38400. Stride-33 pad keeps phase-C reads ~conflict-free.
    __shared__ __align__(16) char smem[38400];
    float* rpart = (float*)smem;
    int*   swin  = (int*)(smem + 4096);
    float* skey  = (float*)(smem + 4608);
    int*   sct   = (int*)(smem + 21504);

    const int t     = threadIdx.x;
    const int lane  = t & 63;
    const int w     = t >> 6;          // 0..7
    const int m     = lane & 15;
    const int quad  = lane >> 4;
    const int g     = w >> 1;          // point-group 0..3
    const int h     = w & 1;           // code-half 0..1
    const int pbase = blockIdx.x * 128 + g * 32;

    // ---- Phase A: x -> norm partials + 8 A-frags (2 rowtiles) -> AGPR ----
    f16x8 Ah00, As00, Ah01, As01;   // rowtile 0, K-halves 0/1
    f16x8 Ah10, As10, Ah11, As11;   // rowtile 1
#define LOADA(TT, HH, FH, FS) {                                            \
    const float* px = x + ((size_t)(pbase + TT * 16 + m)) * D + HH * 32 + quad * 8; \
    const float4 u0 = *(const float4*)px;                                  \
    const float4 u1 = *(const float4*)(px + 4);                            \
    if (h == 0)                                                            \
        rpart[(g * 32 + TT * 16 + m) * 8 + (HH * 4 + quad)] =              \
            sq8(u0.x, u0.y, u0.z, u0.w, u1.x, u1.y, u1.z, u1.w);           \
    MKFRAG16(FH, FS, u0, u1); }
    LOADA(0, 0, Ah00, As00)
    LOADA(0, 1, Ah01, As01)
    LOADA(1, 0, Ah10, As10)
    LOADA(1, 1, Ah11, As11)
#undef LOADA
    PINFA(Ah00); PINFA(As00); PINFA(Ah01); PINFA(As01);
    PINFA(Ah10); PINFA(As10); PINFA(Ah11); PINFA(As11);

    // Persistent zero C-in quad, also in the AGPR half.
    f32x4 ZERO = {0.f, 0.f, 0.f, 0.f};
    PINFA(ZERO);

    // ---- Phase B: 32 tiles; 3-buffer, 2-deep register prefetch ----
    const float FINF = 3.402823466e38f;
    float bk00 = FINF, bk01 = FINF, bk02 = FINF, bk03 = FINF;
    float bk10 = FINF, bk11 = FINF, bk12 = FINF, bk13 = FINF;
    int   bc00 = 0, bc01 = 0, bc02 = 0, bc03 = 0;
    int   bc10 = 0, bc11 = 0, bc12 = 0, bc13 = 0;

    const char* bh = (const char*)ehf + (size_t)h * 65536 + (size_t)lane * 16;
    const char* bs = (const char*)elf + (size_t)h * 65536 + (size_t)lane * 16;
    const float* enp = enorm_h + h * 512 + m;

#define AC1(BK, BC, MV, CV, CT, ENH) {                                     \
    const float kv = __builtin_fmaf(-ISCL, CV, (ENH) - (MV));              \
    if (kv < BK) { BK = kv; BC = (CT); } }

#define COMPUTE(CT, BH0, BH1, BS0, BS1) {                                  \
    const float enh_ = enp[(CT) * 16];   /* issued early, used at AC1 */   \
    __builtin_amdgcn_s_setprio(1);                                         \
    f32x4 m0 = MF(Ah00, BH0, ZERO);  f32x4 m1 = MF(Ah10, BH0, ZERO);       \
    f32x4 c0 = MF(As00, BH0, ZERO);  f32x4 c1 = MF(As10, BH0, ZERO);       \
    m0 = MF(Ah01, BH1, m0);  m1 = MF(Ah11, BH1, m1);                       \
    c0 = MF(As01, BH1, c0);  c1 = MF(As11, BH1, c1);                       \
    c0 = MF(Ah00, BS0, c0);  c1 = MF(Ah10, BS0, c1);                       \
    c0 = MF(Ah01, BS1, c0);  c1 = MF(Ah11, BS1, c1);                       \
    __builtin_amdgcn_s_setprio(0);                                         \
    AC1(bk00, bc00, m0[0], c0[0], CT, enh_)                                \
    AC1(bk01, bc01, m0[1], c0[1], CT, enh_)                                \
    AC1(bk02, bc02, m0[2], c0[2], CT, enh_)                                \
    AC1(bk03, bc03, m0[3], c0[3], CT, enh_)                                \
    AC1(bk10, bc10, m1[0], c1[0], CT, enh_)                                \
    AC1(bk11, bc11, m1[1], c1[1], CT, enh_)                                \
    AC1(bk12, bc12, m1[2], c1[2], CT, enh_)                                \
    AC1(bk13, bc13, m1[3], c1[3], CT, enh_) }

#define LOADB(TT, BH0, BH1, BS0, BS1) {                                    \
    const int ob_ = (TT) * 2048;                                           \
    BH0 = *(const f16x8*)(bh + ob_);                                       \
    BH1 = *(const f16x8*)(bh + ob_ + 1024);                                \
    BS0 = *(const f16x8*)(bs + ob_);                                       \
    BS1 = *(const f16x8*)(bs + ob_ + 1024); }

    f16x8 aBh0, aBh1, aBs0, aBs1;   // buffer 0
    f16x8 bBh0, bBh1, bBs0, bBs1;   // buffer 1
    f16x8 cBh0, cBh1, cBs0, cBs1;   // buffer 2

    // Prologue: tiles 0,1,2 in flight — 2 full bodies of slack before use.
    LOADB(0, aBh0, aBh1, aBs0, aBs1)
    LOADB(1, bBh0, bBh1, bBs0, bBs1)
    LOADB(2, cBh0, cBh1, cBs0, cBs1)

    for (int j = 0; j < 30; j += 3) {
        COMPUTE(j,     aBh0, aBh1, aBs0, aBs1)
        LOADB((j + 3) & 31, aBh0, aBh1, aBs0, aBs1)
        COMPUTE(j + 1, bBh0, bBh1, bBs0, bBs1)
        LOADB((j + 4) & 31, bBh0, bBh1, bBs0, bBs1)
        COMPUTE(j + 2, cBh0, cBh1, cBs0, cBs1)
        LOADB((j + 5) & 31, cBh0, cBh1, cBs0, cBs1)
    }
    COMPUTE(30, aBh0, aBh1, aBs0, aBs1)
    COMPUTE(31, bBh0, bBh1, bBs0, bBs1)
#undef LOADB
#undef COMPUTE
#undef AC1

    // C-layout: row = quad*4 + reg, col = m; class = h*16 + m (32 classes).
#define PUTC(TT, REG, BK, BC) {                                   \
    const int ploc = g * 32 + TT * 16 + quad * 4 + REG;           \
    skey[ploc * 33 + h * 16 + m] = BK;                            \
    sct [ploc * 33 + h * 16 + m] = BC; }
    PUTC(0, 0, bk00, bc00) PUTC(0, 1, bk01, bc01)
    PUTC(0, 2, bk02, bc02) PUTC(0, 3, bk03, bc03)
    PUTC(1, 0, bk10, bc10) PUTC(1, 1, bk11, bc11)
    PUTC(1, 2, bk12, bc12) PUTC(1, 3, bk13, bc13)
#undef PUTC
    __syncthreads();

    // ---- Phase C (t<128): lex (key, idx) combine over 32 classes ----
    if (t < 128) {
        const int p = t;
        const float* rp = rpart + p * 8;
        const float A = ((rp[0] + rp[1]) + (rp[2] + rp[3])) +
                        ((rp[4] + rp[5]) + (rp[6] + rp[7]));
        float fb = FINF;
        int   fi = 0;
#pragma unroll
        for (int c = 0; c < 32; ++c) {
            const float kv = skey[p * 33 + c];
            const int   iv = (c >> 4) * 512 + sct[p * 33 + c] * 16 + (c & 15);
            if (kv < fb || (kv == fb && iv < fi)) { fb = kv; fi = iv; }
        }
        swin[p] = fi;
        float lp = fmaf(2.0f, fb, A);   // ||x-q||^2 = A + 2*key
#pragma unroll
        for (int off = 32; off > 0; off >>= 1) lp += __shfl_down(lp, off, 64);
        if (lane == 0) atomicAdd(loss_out, lp * (1.25f / (float)OUT_ELEMS));
    }
    __syncthreads();

    // ---- Phase D: direct coalesced gather-write. 16 consecutive lanes
    // write the 16 float4 chunks of one point; eT row read is 256 B
    // contiguous from L2-resident eT. Bit-exact row copy. ----
    {
        const float4* eT4 = (const float4*)eT;
        float4* og = (float4*)out + (size_t)blockIdx.x * 2048;
#pragma unroll
        for (int s = 0; s < 4; ++s) {
            const int f  = s * 512 + t;          // 0..2047 float4s
            const int fi = swin[f >> 4];
            og[f] = eT4[(size_t)fi * 16 + (f & 15)];
        }
    }
}

extern "C" void kernel_launch(void* const* d_in, const int* in_sizes, int n_in,
                              void* d_out, int out_size, void* d_ws, size_t ws_size,
                              hipStream_t stream) {
    const float* x   = (const float*)d_in[0];   // [64,32,32,64] fp32
    const float* emb = (const float*)d_in[1];   // [64,1024] fp32
    float* out       = (float*)d_out;           // [quantized | loss]
    char*  ws        = (char*)d_ws;             // needs 528384 B
    float*    eT      = (float*)ws;
    float*    enorm_h = (float*)(ws + 262144);
    _Float16* ehf     = (_Float16*)(ws + 266240);
    _Float16* elf     = (_Float16*)(ws + 397312);
    float* loss_out   = out + OUT_ELEMS;

    vq_prep<<<dim3(K / 64), dim3(256), 0, stream>>>(emb, eT, enorm_h, ehf, elf,
                                                    loss_out);
    vq_main<<<dim3(NPTS / 128), dim3(512), 0, stream>>>(x, eT, enorm_h, ehf,
                                                        elf, out, loss_out);
}

// Round 10
// 105.788 us; speedup vs baseline: 2.4472x; 2.4472x over previous
//
#include <hip/hip_runtime.h>

#define D 64
#define K 1024
#define NPTS 65536
#define OUT_ELEMS (NPTS * D)

typedef _Float16 f16x8 __attribute__((ext_vector_type(8)));
typedef float    f32x4 __attribute__((ext_vector_type(4)));

#define SCL  4096.0f            // 2^12
#define ISCL 0.000244140625f    // 2^-12

// d_ws layout (bytes): eT f32[K][64] @0 (262144) | enorm_half f32[K] @262144
// (4096) | ehf f16 frag-major @266240 (131072) | elf @397312 | end 528384.
//
// Fragment-major layout: for code k, dim d:
//   ct=k>>4, col=k&15, HH=d>>5, r=(d>>3)&3, j=d&7, lane=r*16+col
//   off = ((ct*2+HH)*64 + lane)*8 + j   ( = ct*1024 + HH*512 + lane*8 + j )
// Main-loop lane (quad,m) reads its 16B f16x8 B-fragment for tile ct,
// K-half HH at ehf + (ct*2+HH)*512 + lane*8.

// Scaled f16 2-way split: v = h + ls*2^-12. h = RN16(v); ls = RN16((v-h)*2^12)
// is normal-range -> no subnormal-flush hazard; residual ~2^-24|v|.
static __device__ __forceinline__ void split16(float v, _Float16& h, _Float16& ls) {
    h = (_Float16)v;
    const float r = (v - (float)h) * SCL;   // exact scaling (pow2)
    ls = (_Float16)r;
}

// ---------------------------------------------------------------------------
// Prep (R20 rewrite): 64 blocks x 16 codes (was 16 blocks x 64 — 6% GPU with
// scattered 4B/2B stores). Per block: read emb[d][k0..k0+16) (4KB), then
//   - eT region [k0*64, k0*64+1024) floats: contiguous, float4 stores;
//   - ehf/elf region [ct*1024, ct*1024+1024) halves (ct = blockIdx): the
//     frag-major layout is per-block contiguous by construction -> 8B runs;
//   - enorm: same serial-over-d FP order as before (bit-identical);
//   - loss slot zeroed by block 0.
// All emitted values bit-identical to the old prep; only store patterns and
// grid width change.
// ---------------------------------------------------------------------------
__global__ __launch_bounds__(256) void vq_prep(const float* __restrict__ emb,
                                               float* __restrict__ eT,
                                               float* __restrict__ enorm_h,
                                               _Float16* __restrict__ ehf,
                                               _Float16* __restrict__ elf,
                                               float* __restrict__ loss_out) {
    __shared__ float tile[64][17];     // [d][kk], 16 codes, pad 17
    const int t  = threadIdx.x;
    const int k0 = blockIdx.x * 16;
    const int ct = blockIdx.x;         // frag-major tile index = k0/16

    {   // load: all (d, kk) pairs, 4 per thread
        const int kk = t & 15;
        const int d0 = t >> 4;         // 0..15
#pragma unroll
        for (int i = 0; i < 4; ++i) {
            const int d = i * 16 + d0;
            tile[d][kk] = emb[d * K + k0 + kk];
        }
    }
    __syncthreads();

    {   // eT: thread t writes floats [t*4, t*4+4) of the block's 1024-float
        // region; kk = t>>4, d = (t&15)*4 + j — contiguous float4.
        const int kk = t >> 4;
        const int dbase = (t & 15) * 4;
        float4 v;
        v.x = tile[dbase + 0][kk];
        v.y = tile[dbase + 1][kk];
        v.z = tile[dbase + 2][kk];
        v.w = tile[dbase + 3][kk];
        *(float4*)(eT + (size_t)(k0 + kk) * D + dbase) = v;
    }

    {   // ehf/elf: u = t*4+j indexes the block's 1024-half region directly.
#pragma unroll
        for (int j = 0; j < 4; ++j) {
            const int u     = t * 4 + j;
            const int HH    = u >> 9;
            const int lane_ = (u >> 3) & 63;
            const int jj    = u & 7;
            const int d     = HH * 32 + (lane_ >> 4) * 8 + jj;
            const int kk    = lane_ & 15;
            _Float16 h, ls;
            split16(tile[d][kk], h, ls);
            ehf[ct * 1024 + u] = h;
            elf[ct * 1024 + u] = ls;
        }
    }

    if (t < 16) {   // np add.reduce axis 0: sequential over d (exact order)
        float s = __fmul_rn(tile[0][t], tile[0][t]);
        for (int dd = 1; dd < D; ++dd)
            s = __fadd_rn(s, __fmul_rn(tile[dd][t], tile[dd][t]));
        enorm_h[k0 + t] = 0.5f * s;
    }
    if (blockIdx.x == 0 && t == 0) *loss_out = 0.0f;
}

static __device__ __forceinline__ float sq8(float a, float b, float c, float d,
                                            float e, float f, float g, float h) {
    float r = __fmul_rn(a, a);
    r = __fadd_rn(r, __fmul_rn(b, b));
    r = __fadd_rn(r, __fmul_rn(c, c));
    r = __fadd_rn(r, __fmul_rn(d, d));
    r = __fadd_rn(r, __fmul_rn(e, e));
    r = __fadd_rn(r, __fmul_rn(f, f));
    r = __fadd_rn(r, __fmul_rn(g, g));
    r = __fadd_rn(r, __fmul_rn(h, h));
    return r;
}

#define PINF(v) asm volatile("" : "+v"(v))

#define MF(A, B, C) __builtin_amdgcn_mfma_f32_16x16x32_f16(A, B, C, 0, 0, 0)

#define MKFRAG16(FH, FS, U0, U1) {                        \
    _Float16 h_, s_;                                      \
    split16(U0.x, h_, s_); FH[0]=h_; FS[0]=s_;            \
    split16(U0.y, h_, s_); FH[1]=h_; FS[1]=s_;            \
    split16(U0.z, h_, s_); FH[2]=h_; FS[2]=s_;            \
    split16(U0.w, h_, s_); FH[3]=h_; FS[3]=s_;            \
    split16(U1.x, h_, s_); FH[4]=h_; FS[4]=s_;            \
    split16(U1.y, h_, s_); FH[5]=h_; FS[5]=s_;            \
    split16(U1.z, h_, s_); FH[6]=h_; FS[6]=s_;            \
    split16(U1.w, h_, s_); FH[7]=h_; FS[7]=s_; }

// ---------------------------------------------------------------------------
// Main (R20 = R15 VERBATIM — best measured: 43.4us, FETCH 10.3MB, clean).
// R16-R19 post-mortems closed the register axis: loads can only target the
// 64 arch-VGPR half of the (512,4) unified budget; every structure needing
// more loaded state (E/O stagger, 3-buffer prefetch, AGPR pinning) spilled
// (FETCH 20/21/377MB). R15 sits exactly at the budget. Do not add loaded
// state to this loop.
// ---------------------------------------------------------------------------
__global__ __launch_bounds__(512, 4) void vq_main(const float* __restrict__ x,
        const float* __restrict__ eT, const float* __restrict__ enorm_h,
        const _Float16* __restrict__ ehf, const _Float16* __restrict__ elf,
        float* __restrict__ out, float* __restrict__ loss_out) {
    // LDS: rpart 128x8 f32 @0 (4096) | swin 128 i32 @4096 (512) |
    //      skey 128x33 f32 @4608 (16896) | sct 128x33 i32 @21504 (16896) |
    //      end 38400. Stride-33 pad keeps phase-C reads ~conflict-free.
    __shared__ __align__(16) char smem[38400];
    float* rpart = (float*)smem;
    int*   swin  = (int*)(smem + 4096);
    float* skey  = (float*)(smem + 4608);
    int*   sct   = (int*)(smem + 21504);

    const int t     = threadIdx.x;
    const int lane  = t & 63;
    const int w     = t >> 6;          // 0..7
    const int m     = lane & 15;
    const int quad  = lane >> 4;
    const int g     = w >> 1;          // point-group 0..3
    const int h     = w & 1;           // code-half 0..1
    const int pbase = blockIdx.x * 128 + g * 32;

    // ---- Phase A: x -> norm partials + 8 pinned A-frags (2 rowtiles) ----
    f16x8 Ah00, As00, Ah01, As01;   // rowtile 0, K-halves 0/1
    f16x8 Ah10, As10, Ah11, As11;   // rowtile 1
#define LOADA(TT, HH, FH, FS) {                                            \
    const float* px = x + ((size_t)(pbase + TT * 16 + m)) * D + HH * 32 + quad * 8; \
    const float4 u0 = *(const float4*)px;                                  \
    const float4 u1 = *(const float4*)(px + 4);                            \
    if (h == 0)                                                            \
        rpart[(g * 32 + TT * 16 + m) * 8 + (HH * 4 + quad)] =              \
            sq8(u0.x, u0.y, u0.z, u0.w, u1.x, u1.y, u1.z, u1.w);           \
    MKFRAG16(FH, FS, u0, u1); }
    LOADA(0, 0, Ah00, As00)
    LOADA(0, 1, Ah01, As01)
    LOADA(1, 0, Ah10, As10)
    LOADA(1, 1, Ah11, As11)
#undef LOADA
    PINF(Ah00); PINF(As00); PINF(Ah01); PINF(As01);
    PINF(Ah10); PINF(As10); PINF(Ah11); PINF(As11);

    // Persistent zero C-in register: pinned so the compiler keeps one live
    // quad instead of re-materializing 32 zero-movs per iteration.
    f32x4 ZERO = {0.f, 0.f, 0.f, 0.f};
    PINF(ZERO);

    // ---- Phase B: 32 iterations over this wave's 512 codes, no barriers,
    //      B-frags + enorm software-pipelined one iteration ahead. ----
    const float FINF = 3.402823466e38f;
    float bk00 = FINF, bk01 = FINF, bk02 = FINF, bk03 = FINF;
    float bk10 = FINF, bk11 = FINF, bk12 = FINF, bk13 = FINF;
    int   bc00 = 0, bc01 = 0, bc02 = 0, bc03 = 0;
    int   bc10 = 0, bc11 = 0, bc12 = 0, bc13 = 0;

    const char* bh = (const char*)ehf + (size_t)h * 65536 + (size_t)lane * 16;
    const char* bs = (const char*)elf + (size_t)h * 65536 + (size_t)lane * 16;
    const float* enp = enorm_h + h * 512 + m;

#define COMPUTE(CT, BH0, BH1, BS0, BS1, ENH) {                             \
    f32x4 m0 = MF(Ah00, BH0, ZERO);   /* hh rowtile0, K-chained */         \
    f32x4 m1 = MF(Ah10, BH0, ZERO);   /* hh rowtile1 */                    \
    f32x4 c0 = MF(As00, BH0, ZERO);   /* corr rowtile0, 4-chain */         \
    f32x4 c1 = MF(As10, BH0, ZERO);   /* corr rowtile1 */                  \
    m0 = MF(Ah01, BH1, m0);                                                \
    m1 = MF(Ah11, BH1, m1);                                                \
    c0 = MF(As01, BH1, c0);                                                \
    c1 = MF(As11, BH1, c1);                                                \
    c0 = MF(Ah00, BS0, c0);                                                \
    c1 = MF(Ah10, BS0, c1);                                                \
    c0 = MF(Ah01, BS1, c0);                                                \
    c1 = MF(Ah11, BS1, c1);                                                \
    { const float kv = __builtin_fmaf(-ISCL, c0[0], ENH - m0[0]);          \
      if (kv < bk00) { bk00 = kv; bc00 = (CT); } }                         \
    { const float kv = __builtin_fmaf(-ISCL, c0[1], ENH - m0[1]);          \
      if (kv < bk01) { bk01 = kv; bc01 = (CT); } }                         \
    { const float kv = __builtin_fmaf(-ISCL, c0[2], ENH - m0[2]);          \
      if (kv < bk02) { bk02 = kv; bc02 = (CT); } }                         \
    { const float kv = __builtin_fmaf(-ISCL, c0[3], ENH - m0[3]);          \
      if (kv < bk03) { bk03 = kv; bc03 = (CT); } }                         \
    { const float kv = __builtin_fmaf(-ISCL, c1[0], ENH - m1[0]);          \
      if (kv < bk10) { bk10 = kv; bc10 = (CT); } }                         \
    { const float kv = __builtin_fmaf(-ISCL, c1[1], ENH - m1[1]);          \
      if (kv < bk11) { bk11 = kv; bc11 = (CT); } }                         \
    { const float kv = __builtin_fmaf(-ISCL, c1[2], ENH - m1[2]);          \
      if (kv < bk12) { bk12 = kv; bc12 = (CT); } }                         \
    { const float kv = __builtin_fmaf(-ISCL, c1[3], ENH - m1[3]);          \
      if (kv < bk13) { bk13 = kv; bc13 = (CT); } } }

#define LOADB(TT, BH0, BH1, BS0, BS1, ENH) {                               \
    const int ob_ = (TT) * 2048;                                           \
    BH0 = *(const f16x8*)(bh + ob_);        BH1 = *(const f16x8*)(bh + ob_ + 1024); \
    BS0 = *(const f16x8*)(bs + ob_);        BS1 = *(const f16x8*)(bs + ob_ + 1024); \
    ENH = enp[(TT) * 16]; }

    f16x8 aBh0, aBh1, aBs0, aBs1;  float aEn;   // buffer A
    f16x8 pBh0, pBh1, pBs0, pBs1;  float pEn;   // buffer B

    LOADB(0, aBh0, aBh1, aBs0, aBs1, aEn)       // prologue: tile 0 -> A
    for (int j = 0; j < 16; ++j) {
        const int t1 = 2 * j + 1;
        const int t2 = (2 * j + 2) & 31;        // wrap: harmless re-read
        LOADB(t1, pBh0, pBh1, pBs0, pBs1, pEn)  // prefetch odd tile -> B
        COMPUTE(2 * j, aBh0, aBh1, aBs0, aBs1, aEn)
        LOADB(t2, aBh0, aBh1, aBs0, aBs1, aEn)  // prefetch even tile -> A
        COMPUTE(t1, pBh0, pBh1, pBs0, pBs1, pEn)
    }
#undef LOADB
#undef COMPUTE

    // C-layout: row = quad*4 + reg, col = m; class = h*16 + m (32 classes).
#define PUTC(TT, REG, BK, BC) {                                   \
    const int ploc = g * 32 + TT * 16 + quad * 4 + REG;           \
    skey[ploc * 33 + h * 16 + m] = BK;                            \
    sct [ploc * 33 + h * 16 + m] = BC; }
    PUTC(0, 0, bk00, bc00) PUTC(0, 1, bk01, bc01)
    PUTC(0, 2, bk02, bc02) PUTC(0, 3, bk03, bc03)
    PUTC(1, 0, bk10, bc10) PUTC(1, 1, bk11, bc11)
    PUTC(1, 2, bk12, bc12) PUTC(1, 3, bk13, bc13)
#undef PUTC
    __syncthreads();

    // ---- Phase C (t<128): lex (key, idx) combine over 32 classes ----
    if (t < 128) {
        const int p = t;
        const float* rp = rpart + p * 8;
        const float A = ((rp[0] + rp[1]) + (rp[2] + rp[3])) +
                        ((rp[4] + rp[5]) + (rp[6] + rp[7]));
        float fb = FINF;
        int   fi = 0;
#pragma unroll
        for (int c = 0; c < 32; ++c) {
            const float kv = skey[p * 33 + c];
            const int   iv = (c >> 4) * 512 + sct[p * 33 + c] * 16 + (c & 15);
            if (kv < fb || (kv == fb && iv < fi)) { fb = kv; fi = iv; }
        }
        swin[p] = fi;
        float lp = fmaf(2.0f, fb, A);   // ||x-q||^2 = A + 2*key
#pragma unroll
        for (int off = 32; off > 0; off >>= 1) lp += __shfl_down(lp, off, 64);
        if (lane == 0) atomicAdd(loss_out, lp * (1.25f / (float)OUT_ELEMS));
    }
    __syncthreads();

    // ---- Phase D: direct coalesced gather-write. 16 consecutive lanes
    // write the 16 float4 chunks of one point; eT row read is 256 B
    // contiguous from L2-resident eT. Bit-exact row copy. ----
    {
        const float4* eT4 = (const float4*)eT;
        float4* og = (float4*)out + (size_t)blockIdx.x * 2048;
#pragma unroll
        for (int s = 0; s < 4; ++s) {
            const int f  = s * 512 + t;          // 0..2047 float4s
            const int fi = swin[f >> 4];
            og[f] = eT4[(size_t)fi * 16 + (f & 15)];
        }
    }
}

extern "C" void kernel_launch(void* const* d_in, const int* in_sizes, int n_in,
                              void* d_out, int out_size, void* d_ws, size_t ws_size,
                              hipStream_t stream) {
    const float* x   = (const float*)d_in[0];   // [64,32,32,64] fp32
    const float* emb = (const float*)d_in[1];   // [64,1024] fp32
    float* out       = (float*)d_out;           // [quantized | loss]
    char*  ws        = (char*)d_ws;             // needs 528384 B
    float*    eT      = (float*)ws;
    float*    enorm_h = (float*)(ws + 262144);
    _Float16* ehf     = (_Float16*)(ws + 266240);
    _Float16* elf     = (_Float16*)(ws + 397312);
    float* loss_out   = out + OUT_ELEMS;

    vq_prep<<<dim3(K / 16), dim3(256), 0, stream>>>(emb, eT, enorm_h, ehf, elf,
                                                    loss_out);
    vq_main<<<dim3(NPTS / 128), dim3(512), 0, stream>>>(x, eT, enorm_h, ehf,
                                                        elf, out, loss_out);
}